// Round 7
// baseline (554.548 us; speedup 1.0000x reference)
//
#include <hip/hip_runtime.h>
#include <hip/hip_bf16.h>
#include <stdint.h>

#define D_EMBED 1024
#define D_HID   4096
#define N_TOK   4096
#define N_EXP   8
#define CAP     4096
#define NROWA   8448            // 8192 rows + slack for 256-row tile overshoot

typedef __attribute__((ext_vector_type(4))) float f32x4;
typedef __attribute__((ext_vector_type(8))) short bf16x8;

__device__ __forceinline__ unsigned short f2bf(float f) {
    unsigned int u = __builtin_bit_cast(unsigned int, f);
    u += 0x7fffu + ((u >> 16) & 1u);          // round-to-nearest-even
    return (unsigned short)(u >> 16);
}

__device__ __forceinline__ void gload_lds16(const void* g, void* l) {
    __builtin_amdgcn_global_load_lds(
        (const __attribute__((address_space(1))) unsigned int*)g,
        (__attribute__((address_space(3))) unsigned int*)l,
        16, 0, 0);
}

// ------- pack W [E][R][C] f32 -> tiled bf16 [E][R/8 ks][C][8 j] (for W2) -------
__global__ __launch_bounds__(256) void pack_w(const float* __restrict__ W,
                                              unsigned short* __restrict__ out, int R, int C) {
    int e = blockIdx.z, kb = blockIdx.y, cb = blockIdx.x;
    const float* Wp = W + (size_t)e * R * C + (size_t)(kb * 64) * C + cb * 64;
    unsigned short* op = out + (size_t)e * R * C;
    __shared__ unsigned short lds[64][72];
    int t = threadIdx.x;
    int r = t >> 2;
    int c0 = (t & 3) << 4;
    const float* src = Wp + (size_t)r * C + c0;
#pragma unroll
    for (int i = 0; i < 2; ++i) {
        f32x4 a = *reinterpret_cast<const f32x4*>(src + i * 8);
        f32x4 b = *reinterpret_cast<const f32x4*>(src + i * 8 + 4);
        bf16x8 o;
        o[0]=(short)f2bf(a[0]); o[1]=(short)f2bf(a[1]); o[2]=(short)f2bf(a[2]); o[3]=(short)f2bf(a[3]);
        o[4]=(short)f2bf(b[0]); o[5]=(short)f2bf(b[1]); o[6]=(short)f2bf(b[2]); o[7]=(short)f2bf(b[3]);
        *reinterpret_cast<bf16x8*>(&lds[r][c0 + i * 8]) = o;
    }
    __syncthreads();
#pragma unroll
    for (int i = 0; i < 2; ++i) {
        int cell = i * 256 + t;
        int ksl = cell >> 6, col = cell & 63;
        bf16x8 o;
#pragma unroll
        for (int j = 0; j < 8; ++j) o[j] = (short)lds[ksl * 8 + j][col];
        *reinterpret_cast<bf16x8*>(op + ((size_t)(kb * 8 + ksl) * C + cb * 64 + col) * 8) = o;
    }
}

// ------- pack W1,W3 interleaved at 16-col granularity -------
__global__ __launch_bounds__(256) void pack_w13(const float* __restrict__ W1,
                                                const float* __restrict__ W3,
                                                unsigned short* __restrict__ out) {
    int e = blockIdx.z, kb = blockIdx.y, cb = blockIdx.x;   // cb: 64 packed cols = 32 real each
    size_t ebase = (size_t)e * D_EMBED * D_HID;
    const float* b1 = W1 + ebase + (size_t)(kb * 64) * D_HID + cb * 32;
    const float* b3 = W3 + ebase + (size_t)(kb * 64) * D_HID + cb * 32;
    unsigned short* op = out + (size_t)e * D_EMBED * 2 * D_HID;
    __shared__ unsigned short lds[64][72];   // cols: [W1a 16][W1b 16][W3a 16][W3b 16]
    int t = threadIdx.x;
    int r = t >> 2, ck = t & 3;
    const float* src = (ck >= 2 ? b3 : b1) + (size_t)r * D_HID + (ck & 1) * 16;
#pragma unroll
    for (int i = 0; i < 2; ++i) {
        f32x4 a = *reinterpret_cast<const f32x4*>(src + i * 8);
        f32x4 b = *reinterpret_cast<const f32x4*>(src + i * 8 + 4);
        bf16x8 o;
        o[0]=(short)f2bf(a[0]); o[1]=(short)f2bf(a[1]); o[2]=(short)f2bf(a[2]); o[3]=(short)f2bf(a[3]);
        o[4]=(short)f2bf(b[0]); o[5]=(short)f2bf(b[1]); o[6]=(short)f2bf(b[2]); o[7]=(short)f2bf(b[3]);
        *reinterpret_cast<bf16x8*>(&lds[r][ck * 16 + i * 8]) = o;
    }
    __syncthreads();
#pragma unroll
    for (int i = 0; i < 2; ++i) {
        int cell = i * 256 + t;
        int ksl = cell >> 6, pcp = cell & 63;
        int lcol = ((pcp >> 4) & 1) * 32 + ((pcp >> 5) & 1) * 16 + (pcp & 15);
        bf16x8 o;
#pragma unroll
        for (int j = 0; j < 8; ++j) o[j] = (short)lds[ksl * 8 + j][lcol];
        *reinterpret_cast<bf16x8*>(op + ((size_t)(kb * 8 + ksl) * (2 * D_HID) + cb * 64 + pcp) * 8) = o;
    }
}

// ---------------- gating ----------------
__global__ __launch_bounds__(256) void gate_kernel(const float* __restrict__ x,
                                                   const float* __restrict__ Wg,
                                                   int* __restrict__ counts,
                                                   int* __restrict__ toks,
                                                   float* __restrict__ wgts,
                                                   int* __restrict__ slots) {
    int wave = threadIdx.x >> 6;
    int lane = threadIdx.x & 63;
    int tok = blockIdx.x * 4 + wave;
    const float* xp = x + (size_t)tok * D_EMBED;
    float acc[8] = {0, 0, 0, 0, 0, 0, 0, 0};
#pragma unroll
    for (int i = 0; i < 16; ++i) {
        int d = lane + 64 * i;
        float xv = xp[d];
        f32x4 w0 = *reinterpret_cast<const f32x4*>(Wg + (size_t)d * 8);
        f32x4 w1 = *reinterpret_cast<const f32x4*>(Wg + (size_t)d * 8 + 4);
        acc[0] += xv * w0[0]; acc[1] += xv * w0[1]; acc[2] += xv * w0[2]; acc[3] += xv * w0[3];
        acc[4] += xv * w1[0]; acc[5] += xv * w1[1]; acc[6] += xv * w1[2]; acc[7] += xv * w1[3];
    }
#pragma unroll
    for (int e = 0; e < 8; ++e)
        for (int s = 32; s; s >>= 1) acc[e] += __shfl_xor(acc[e], s, 64);
    if (lane == 0) {
        int i0 = 0; float v0 = acc[0];
#pragma unroll
        for (int e = 1; e < 8; ++e) if (acc[e] > v0) { v0 = acc[e]; i0 = e; }
        int i1 = -1; float v1 = -1e30f;
#pragma unroll
        for (int e = 0; e < 8; ++e) if (e != i0 && acc[e] > v1) { v1 = acc[e]; i1 = e; }
        float ex = __expf(v1 - v0);
        float w0 = 1.0f / (1.0f + ex);
        float w1 = 1.0f - w0;
        int p0 = atomicAdd(&counts[i0], 1);
        toks[i0 * CAP + p0] = tok; wgts[i0 * CAP + p0] = w0; slots[i0 * CAP + p0] = 0;
        int p1 = atomicAdd(&counts[i1], 1);
        toks[i1 * CAP + p1] = tok; wgts[i1 * CAP + p1] = w1; slots[i1 * CAP + p1] = 1;
    }
}

__global__ void prefix_kernel(const int* __restrict__ counts, int* __restrict__ offsets) {
    if (threadIdx.x == 0) {
        int s = 0;
        for (int e = 0; e < N_EXP; ++e) { offsets[e] = s; s += counts[e]; }
    }
}

__global__ __launch_bounds__(256) void build_map_kernel(const int* __restrict__ counts,
                                                        const int* __restrict__ offsets,
                                                        const int* __restrict__ toks,
                                                        const int* __restrict__ slots,
                                                        int* __restrict__ tok2row) {
    int i = blockIdx.x * 256 + threadIdx.x;
    int e = i >> 12, pos = i & (CAP - 1);
    if (pos < counts[e])
        tok2row[toks[i] * 2 + slots[i]] = offsets[e] + pos;
}

// ------- gather x rows into compacted k-packed A: xg[s][row][8] -------
__global__ __launch_bounds__(256) void gather_x_kernel(
    const float* __restrict__ x,
    const int* __restrict__ counts, const int* __restrict__ offsets,
    const int* __restrict__ toks,
    unsigned short* __restrict__ xg) {
    int rt = blockIdx.x;
    int e = -1, base = 0, rowbase = 0, cnt = 0;
    for (int ee = 0; ee < N_EXP; ++ee) {
        int c = counts[ee];
        int nt = (c + 63) >> 6;
        if (rt < base + nt) { e = ee; rowbase = (rt - base) << 6; cnt = c; break; }
        base += nt;
    }
    if (e < 0) return;
    int off = offsets[e];
    int kb = blockIdx.y;
    __shared__ unsigned short lds[64][72];
    int t = threadIdx.x;
    int r = t >> 2, ck = t & 3;
    int pos = rowbase + r;
    unsigned short tmp[16];
    if (pos < cnt) {
        int tok = toks[e * CAP + pos];
        const float* src = x + (size_t)tok * D_EMBED + kb * 64 + ck * 16;
#pragma unroll
        for (int i = 0; i < 4; ++i) {
            f32x4 v = *reinterpret_cast<const f32x4*>(src + i * 4);
#pragma unroll
            for (int j = 0; j < 4; ++j) tmp[i * 4 + j] = f2bf(v[j]);
        }
    } else {
#pragma unroll
        for (int i = 0; i < 16; ++i) tmp[i] = 0;
    }
#pragma unroll
    for (int i = 0; i < 16; ++i) lds[r][ck * 16 + i] = tmp[i];
    __syncthreads();
    int sl = t >> 5, rr = (t & 31) * 2;
#pragma unroll
    for (int w = 0; w < 2; ++w) {
        int rw = rr + w;
        if (rowbase + rw >= cnt) continue;
        bf16x8 o;
#pragma unroll
        for (int j = 0; j < 8; ++j) o[j] = (short)lds[rw][sl * 8 + j];
        *reinterpret_cast<bf16x8*>(xg + ((size_t)(kb * 8 + sl) * NROWA + off + rowbase + rw) * 8) = o;
    }
}

// ======= GEMM1: 256x256p, BK=64, 8 waves (2Mx4N), depth-2 counted-vmcnt pipeline =======
// grid (x = packed coltile 32, y = rowtile 39): XCD = x%8 -> B panel pinned per XCD
__global__ __launch_bounds__(512, 1) void gemm1_kernel(
    const unsigned short* __restrict__ xg,
    const unsigned short* __restrict__ wt13,
    const int* __restrict__ counts, const int* __restrict__ offsets,
    const float* __restrict__ wgts,
    unsigned short* __restrict__ hp) {
    int rt = blockIdx.y;
    int e = -1, base = 0, rowbase = 0, cnt = 0;
#pragma unroll 1
    for (int ee = 0; ee < N_EXP; ++ee) {
        int c = counts[ee];
        int nt = (c + 255) >> 8;
        if (rt < base + nt) { e = ee; rowbase = (rt - base) << 8; cnt = c; break; }
        base += nt;
    }
    if (e < 0) return;
    int off = offsets[e];
    int colp = blockIdx.x * 256;            // packed col base

    __shared__ __align__(16) char lds[2][65536];    // per buf: A 32K | B 32K

    int t = threadIdx.x, lane = t & 63, w = t >> 6;  // 8 waves
    int wr = w >> 2, wc = w & 3;                     // wr 0..1 (128 rows), wc 0..3 (64 pcols)
    int q = lane >> 4, p = lane & 15;

    const unsigned short* wB = wt13 + (size_t)e * D_EMBED * 2 * D_HID;
    const unsigned short* pA = xg + (size_t)(off + rowbase) * 8;

    f32x4 acc[8][4] = {};

    auto SA = [&](char* L, int kt) {        // 4 loads/thread: A slice w of 256 rows
        size_t sl = (size_t)(kt * 8 + w);
#pragma unroll
        for (int i = 0; i < 4; ++i)
            gload_lds16(pA + (sl * NROWA + i * 64 + lane) * 8, L + (w * 4 + i) * 1024);
    };
    auto SB = [&](char* L, int kt) {        // 4 loads/thread
        size_t sl = (size_t)(kt * 8 + w);
#pragma unroll
        for (int i = 0; i < 4; ++i)
            gload_lds16(wB + (sl * (2 * D_HID) + colp + i * 64 + lane) * 8,
                        L + 32768 + (w * 4 + i) * 1024);
    };
    auto PHASE = [&](const char* L, int ks) {
        bf16x8 af[8], bfr[4];
#pragma unroll
        for (int m = 0; m < 8; ++m)
            af[m] = *reinterpret_cast<const bf16x8*>(L + (ks * 4 + q) * 4096 + (wr * 128 + m * 16 + p) * 16);
#pragma unroll
        for (int n = 0; n < 4; ++n)
            bfr[n] = *reinterpret_cast<const bf16x8*>(L + 32768 + (ks * 4 + q) * 4096 + (wc * 64 + n * 16 + p) * 16);
        __builtin_amdgcn_s_setprio(1);
#pragma unroll
        for (int n = 0; n < 4; ++n)
#pragma unroll
            for (int m = 0; m < 8; ++m)
                acc[m][n] = __builtin_amdgcn_mfma_f32_16x16x32_bf16(af[m], bfr[n], acc[m][n], 0, 0, 0);
        __builtin_amdgcn_s_setprio(0);
    };

    // depth-2 prologue: tiles 0 and 1 in flight (16 loads/thread)
    SA(&lds[0][0], 0); SB(&lds[0][0], 0);
    SA(&lds[1][0], 1); SB(&lds[1][0], 1);
#pragma unroll 1
    for (int kt = 0; kt < 16; ++kt) {       // K=1024 / BK=64
        // counted wait: tile kt landed (8 newest, for tile kt+1, may still fly)
        if (kt < 15) asm volatile("s_waitcnt vmcnt(8)" ::: "memory");
        else         asm volatile("s_waitcnt vmcnt(0)" ::: "memory");
        __builtin_amdgcn_s_barrier();
        asm volatile("" ::: "memory");
        char* Lc = &lds[kt & 1][0];
        PHASE(Lc, 0);
        PHASE(Lc, 1);
        asm volatile("" ::: "memory");
        __builtin_amdgcn_s_barrier();       // all waves done reading Lc
        asm volatile("" ::: "memory");
        if (kt < 14) { SA(Lc, kt + 2); SB(Lc, kt + 2); }   // refill freed buffer
    }

    // epilogue: pcol-frag pairs (even n = W1, odd n = W3) -> SwiGLU -> hp (k-packed)
#pragma unroll
    for (int m = 0; m < 8; ++m) {
#pragma unroll
        for (int reg = 0; reg < 4; ++reg) {
            int rl = wr * 128 + m * 16 + q * 4 + reg;
            int grow = rowbase + rl;
            if (grow >= cnt) continue;
            float wgt = wgts[e * CAP + grow];
            size_t row = (size_t)(off + grow);
#pragma unroll
            for (int np = 0; np < 2; ++np) {
                float a1 = acc[m][2 * np][reg];
                float a3 = acc[m][2 * np + 1][reg];
                float hv = (a1 / (1.0f + __expf(-a1))) * a3 * wgt;
                int rc = (blockIdx.x * 8 + wc * 2 + np) * 16 + p;   // real col
                hp[((size_t)(rc >> 3) * NROWA + row) * 8 + (rc & 7)] = f2bf(hv);
            }
        }
    }
}

// ======= GEMM2: 256x256, BK=64, split-K=4, same depth-2 counted-vmcnt pipeline =======
// grid (x = coltile 4, y = rowtile 39, z = split 4)
__global__ __launch_bounds__(512, 1) void gemm2_kernel(
    const unsigned short* __restrict__ hp,
    const unsigned short* __restrict__ wt2,
    const int* __restrict__ counts, const int* __restrict__ offsets,
    float* __restrict__ pbuf) {
    int rt = blockIdx.y;
    int e = -1, base = 0, rowbase = 0, cnt = 0;
#pragma unroll 1
    for (int ee = 0; ee < N_EXP; ++ee) {
        int c = counts[ee];
        int nt = (c + 255) >> 8;
        if (rt < base + nt) { e = ee; rowbase = (rt - base) << 8; cnt = c; break; }
        base += nt;
    }
    if (e < 0) return;
    int off = offsets[e];
    int colb = blockIdx.x * 256;
    int s2 = blockIdx.z;

    __shared__ __align__(16) char lds[2][65536];

    int t = threadIdx.x, lane = t & 63, w = t >> 6;
    int wr = w >> 2, wc = w & 3;
    int q = lane >> 4, p = lane & 15;

    const unsigned short* wB = wt2 + (size_t)e * D_HID * D_EMBED;
    const unsigned short* pA = hp + (size_t)(off + rowbase) * 8;

    f32x4 acc[8][4] = {};

    auto SA = [&](char* L, int kt) {
        size_t sl = (size_t)(s2 * 128 + kt * 8 + w);
#pragma unroll
        for (int i = 0; i < 4; ++i)
            gload_lds16(pA + (sl * NROWA + i * 64 + lane) * 8, L + (w * 4 + i) * 1024);
    };
    auto SB = [&](char* L, int kt) {
        size_t sl = (size_t)(s2 * 128 + kt * 8 + w);
#pragma unroll
        for (int i = 0; i < 4; ++i)
            gload_lds16(wB + (sl * D_EMBED + colb + i * 64 + lane) * 8,
                        L + 32768 + (w * 4 + i) * 1024);
    };
    auto PHASE = [&](const char* L, int ks) {
        bf16x8 af[8], bfr[4];
#pragma unroll
        for (int m = 0; m < 8; ++m)
            af[m] = *reinterpret_cast<const bf16x8*>(L + (ks * 4 + q) * 4096 + (wr * 128 + m * 16 + p) * 16);
#pragma unroll
        for (int n = 0; n < 4; ++n)
            bfr[n] = *reinterpret_cast<const bf16x8*>(L + 32768 + (ks * 4 + q) * 4096 + (wc * 64 + n * 16 + p) * 16);
        __builtin_amdgcn_s_setprio(1);
#pragma unroll
        for (int n = 0; n < 4; ++n)
#pragma unroll
            for (int m = 0; m < 8; ++m)
                acc[m][n] = __builtin_amdgcn_mfma_f32_16x16x32_bf16(af[m], bfr[n], acc[m][n], 0, 0, 0);
        __builtin_amdgcn_s_setprio(0);
    };

    SA(&lds[0][0], 0); SB(&lds[0][0], 0);
    SA(&lds[1][0], 1); SB(&lds[1][0], 1);
#pragma unroll 1
    for (int kt = 0; kt < 16; ++kt) {       // 1024 k per split / BK=64
        if (kt < 15) asm volatile("s_waitcnt vmcnt(8)" ::: "memory");
        else         asm volatile("s_waitcnt vmcnt(0)" ::: "memory");
        __builtin_amdgcn_s_barrier();
        asm volatile("" ::: "memory");
        char* Lc = &lds[kt & 1][0];
        PHASE(Lc, 0);
        PHASE(Lc, 1);
        asm volatile("" ::: "memory");
        __builtin_amdgcn_s_barrier();
        asm volatile("" ::: "memory");
        if (kt < 14) { SA(Lc, kt + 2); SB(Lc, kt + 2); }
    }

    float* pb = pbuf + (size_t)s2 * 8192 * D_EMBED;
#pragma unroll
    for (int m = 0; m < 8; ++m)
#pragma unroll
        for (int reg = 0; reg < 4; ++reg) {
            int rl = wr * 128 + m * 16 + q * 4 + reg;
            int grow = rowbase + rl;
            if (grow >= cnt) continue;
            float* dst = pb + (size_t)(off + grow) * D_EMBED + colb + wc * 64;
#pragma unroll
            for (int n = 0; n < 4; ++n) dst[n * 16 + p] = acc[m][n][reg];
        }
}

// ---------------- combine: out[tok] = sum over 2 rows x 4 k-splits ----------------
__global__ __launch_bounds__(256) void combine_kernel(const float* __restrict__ pbuf,
                                                      const int* __restrict__ tok2row,
                                                      float* __restrict__ out) {
    int i = blockIdx.x * 256 + threadIdx.x;
    int tok = i >> 8, c = (i & 255) * 4;
    int r0 = tok2row[tok * 2], r1 = tok2row[tok * 2 + 1];
    const size_t SP = (size_t)8192 * D_EMBED;
    f32x4 s = {0.f, 0.f, 0.f, 0.f};
#pragma unroll
    for (int sp = 0; sp < 4; ++sp) {
        f32x4 a = *reinterpret_cast<const f32x4*>(pbuf + sp * SP + (size_t)r0 * D_EMBED + c);
        f32x4 b = *reinterpret_cast<const f32x4*>(pbuf + sp * SP + (size_t)r1 * D_EMBED + c);
        s = s + a + b;
    }
    *reinterpret_cast<f32x4*>(out + (size_t)tok * D_EMBED + c) = s;
}

extern "C" void kernel_launch(void* const* d_in, const int* in_sizes, int n_in,
                              void* d_out, int out_size, void* d_ws, size_t ws_size,
                              hipStream_t stream) {
    const float* x  = (const float*)d_in[0];
    const float* Wg = (const float*)d_in[1];
    const float* W1 = (const float*)d_in[2];
    const float* W3 = (const float*)d_in[3];
    const float* W2 = (const float*)d_in[4];
    float* out = (float*)d_out;

    char* ws = (char*)d_ws;
    size_t szW = (size_t)N_EXP * D_EMBED * D_HID;
    unsigned short* wt13 = (unsigned short*)ws; ws += szW * 2 * 2;     // 128 MB
    unsigned short* wt2  = (unsigned short*)ws; ws += szW * 2;         // 64 MB
    unsigned short* hp   = (unsigned short*)ws; ws += (size_t)(D_HID / 8) * NROWA * 8 * 2;
    unsigned short* xg   = (unsigned short*)ws; ws += (size_t)(D_EMBED / 8) * NROWA * 8 * 2;
    int*   toks    = (int*)ws;   ws += (size_t)N_EXP * CAP * 4;
    float* wgts    = (float*)ws; ws += (size_t)N_EXP * CAP * 4;
    int*   slots   = (int*)ws;   ws += (size_t)N_EXP * CAP * 4;
    int*   tok2row = (int*)ws;   ws += (size_t)N_TOK * 2 * 4;
    int*   counts  = (int*)ws;   ws += 8 * 4;
    int*   offsets = (int*)ws;   ws += 8 * 4;
    // pbuf (128 MB: 4 splits x 8192 x 1024 f32) aliases wt13 (128 MB, dead after gemm1)
    float* pbuf = (float*)wt13;

    hipMemsetAsync(counts, 0, 8 * sizeof(int), stream);

    pack_w13<<<dim3(128, 16, N_EXP), 256, 0, stream>>>(W1, W3, wt13);
    pack_w<<<dim3(D_EMBED / 64, D_HID / 64, N_EXP), 256, 0, stream>>>(W2, wt2, D_HID, D_EMBED);
    gate_kernel<<<N_TOK / 4, 256, 0, stream>>>(x, Wg, counts, toks, wgts, slots);
    prefix_kernel<<<1, 64, 0, stream>>>(counts, offsets);
    build_map_kernel<<<(N_EXP * CAP) / 256, 256, 0, stream>>>(counts, offsets, toks, slots, tok2row);
    gather_x_kernel<<<dim3(136, D_EMBED / 64), 256, 0, stream>>>(x, counts, offsets, toks, xg);
    gemm1_kernel<<<dim3(32, 39), 512, 0, stream>>>(xg, wt13, counts, offsets, wgts, hp);
    gemm2_kernel<<<dim3(4, 39, 4), 512, 0, stream>>>(hp, wt2, counts, offsets, pbuf);
    combine_kernel<<<(N_TOK * 256) / 256, 256, 0, stream>>>(pbuf, tok2row, out);
}

// Round 8
// 550.317 us; speedup vs baseline: 1.0077x; 1.0077x over previous
//
#include <hip/hip_runtime.h>
#include <hip/hip_bf16.h>
#include <stdint.h>

#define D_EMBED 1024
#define D_HID   4096
#define N_TOK   4096
#define N_EXP   8
#define CAP     4096
#define NROWA   8448            // 8192 rows + slack for 256-row tile overshoot

typedef __attribute__((ext_vector_type(4))) float f32x4;
typedef __attribute__((ext_vector_type(8))) short bf16x8;

__device__ __forceinline__ unsigned short f2bf(float f) {
    unsigned int u = __builtin_bit_cast(unsigned int, f);
    u += 0x7fffu + ((u >> 16) & 1u);          // round-to-nearest-even
    return (unsigned short)(u >> 16);
}

__device__ __forceinline__ void gload_lds16(const void* g, void* l) {
    __builtin_amdgcn_global_load_lds(
        (const __attribute__((address_space(1))) unsigned int*)g,
        (__attribute__((address_space(3))) unsigned int*)l,
        16, 0, 0);
}

// ------- pack W [E][R][C] f32 -> tiled bf16 [E][R/8 ks][C][8 j] (for W2) -------
__global__ __launch_bounds__(256) void pack_w(const float* __restrict__ W,
                                              unsigned short* __restrict__ out, int R, int C) {
    int e = blockIdx.z, kb = blockIdx.y, cb = blockIdx.x;
    const float* Wp = W + (size_t)e * R * C + (size_t)(kb * 64) * C + cb * 64;
    unsigned short* op = out + (size_t)e * R * C;
    __shared__ unsigned short lds[64][72];
    int t = threadIdx.x;
    int r = t >> 2;
    int c0 = (t & 3) << 4;
    const float* src = Wp + (size_t)r * C + c0;
#pragma unroll
    for (int i = 0; i < 2; ++i) {
        f32x4 a = *reinterpret_cast<const f32x4*>(src + i * 8);
        f32x4 b = *reinterpret_cast<const f32x4*>(src + i * 8 + 4);
        bf16x8 o;
        o[0]=(short)f2bf(a[0]); o[1]=(short)f2bf(a[1]); o[2]=(short)f2bf(a[2]); o[3]=(short)f2bf(a[3]);
        o[4]=(short)f2bf(b[0]); o[5]=(short)f2bf(b[1]); o[6]=(short)f2bf(b[2]); o[7]=(short)f2bf(b[3]);
        *reinterpret_cast<bf16x8*>(&lds[r][c0 + i * 8]) = o;
    }
    __syncthreads();
#pragma unroll
    for (int i = 0; i < 2; ++i) {
        int cell = i * 256 + t;
        int ksl = cell >> 6, col = cell & 63;
        bf16x8 o;
#pragma unroll
        for (int j = 0; j < 8; ++j) o[j] = (short)lds[ksl * 8 + j][col];
        *reinterpret_cast<bf16x8*>(op + ((size_t)(kb * 8 + ksl) * C + cb * 64 + col) * 8) = o;
    }
}

// ------- pack W1,W3 interleaved at 16-col granularity -------
__global__ __launch_bounds__(256) void pack_w13(const float* __restrict__ W1,
                                                const float* __restrict__ W3,
                                                unsigned short* __restrict__ out) {
    int e = blockIdx.z, kb = blockIdx.y, cb = blockIdx.x;   // cb: 64 packed cols = 32 real each
    size_t ebase = (size_t)e * D_EMBED * D_HID;
    const float* b1 = W1 + ebase + (size_t)(kb * 64) * D_HID + cb * 32;
    const float* b3 = W3 + ebase + (size_t)(kb * 64) * D_HID + cb * 32;
    unsigned short* op = out + (size_t)e * D_EMBED * 2 * D_HID;
    __shared__ unsigned short lds[64][72];   // cols: [W1a 16][W1b 16][W3a 16][W3b 16]
    int t = threadIdx.x;
    int r = t >> 2, ck = t & 3;
    const float* src = (ck >= 2 ? b3 : b1) + (size_t)r * D_HID + (ck & 1) * 16;
#pragma unroll
    for (int i = 0; i < 2; ++i) {
        f32x4 a = *reinterpret_cast<const f32x4*>(src + i * 8);
        f32x4 b = *reinterpret_cast<const f32x4*>(src + i * 8 + 4);
        bf16x8 o;
        o[0]=(short)f2bf(a[0]); o[1]=(short)f2bf(a[1]); o[2]=(short)f2bf(a[2]); o[3]=(short)f2bf(a[3]);
        o[4]=(short)f2bf(b[0]); o[5]=(short)f2bf(b[1]); o[6]=(short)f2bf(b[2]); o[7]=(short)f2bf(b[3]);
        *reinterpret_cast<bf16x8*>(&lds[r][ck * 16 + i * 8]) = o;
    }
    __syncthreads();
#pragma unroll
    for (int i = 0; i < 2; ++i) {
        int cell = i * 256 + t;
        int ksl = cell >> 6, pcp = cell & 63;
        int lcol = ((pcp >> 4) & 1) * 32 + ((pcp >> 5) & 1) * 16 + (pcp & 15);
        bf16x8 o;
#pragma unroll
        for (int j = 0; j < 8; ++j) o[j] = (short)lds[ksl * 8 + j][lcol];
        *reinterpret_cast<bf16x8*>(op + ((size_t)(kb * 8 + ksl) * (2 * D_HID) + cb * 64 + pcp) * 8) = o;
    }
}

// ---------------- gating ----------------
__global__ __launch_bounds__(256) void gate_kernel(const float* __restrict__ x,
                                                   const float* __restrict__ Wg,
                                                   int* __restrict__ counts,
                                                   int* __restrict__ toks,
                                                   float* __restrict__ wgts,
                                                   int* __restrict__ slots) {
    int wave = threadIdx.x >> 6;
    int lane = threadIdx.x & 63;
    int tok = blockIdx.x * 4 + wave;
    const float* xp = x + (size_t)tok * D_EMBED;
    float acc[8] = {0, 0, 0, 0, 0, 0, 0, 0};
#pragma unroll
    for (int i = 0; i < 16; ++i) {
        int d = lane + 64 * i;
        float xv = xp[d];
        f32x4 w0 = *reinterpret_cast<const f32x4*>(Wg + (size_t)d * 8);
        f32x4 w1 = *reinterpret_cast<const f32x4*>(Wg + (size_t)d * 8 + 4);
        acc[0] += xv * w0[0]; acc[1] += xv * w0[1]; acc[2] += xv * w0[2]; acc[3] += xv * w0[3];
        acc[4] += xv * w1[0]; acc[5] += xv * w1[1]; acc[6] += xv * w1[2]; acc[7] += xv * w1[3];
    }
#pragma unroll
    for (int e = 0; e < 8; ++e)
        for (int s = 32; s; s >>= 1) acc[e] += __shfl_xor(acc[e], s, 64);
    if (lane == 0) {
        int i0 = 0; float v0 = acc[0];
#pragma unroll
        for (int e = 1; e < 8; ++e) if (acc[e] > v0) { v0 = acc[e]; i0 = e; }
        int i1 = -1; float v1 = -1e30f;
#pragma unroll
        for (int e = 0; e < 8; ++e) if (e != i0 && acc[e] > v1) { v1 = acc[e]; i1 = e; }
        float ex = __expf(v1 - v0);
        float w0 = 1.0f / (1.0f + ex);
        float w1 = 1.0f - w0;
        int p0 = atomicAdd(&counts[i0], 1);
        toks[i0 * CAP + p0] = tok; wgts[i0 * CAP + p0] = w0; slots[i0 * CAP + p0] = 0;
        int p1 = atomicAdd(&counts[i1], 1);
        toks[i1 * CAP + p1] = tok; wgts[i1 * CAP + p1] = w1; slots[i1 * CAP + p1] = 1;
    }
}

__global__ void prefix_kernel(const int* __restrict__ counts, int* __restrict__ offsets) {
    if (threadIdx.x == 0) {
        int s = 0;
        for (int e = 0; e < N_EXP; ++e) { offsets[e] = s; s += counts[e]; }
    }
}

__global__ __launch_bounds__(256) void build_map_kernel(const int* __restrict__ counts,
                                                        const int* __restrict__ offsets,
                                                        const int* __restrict__ toks,
                                                        const int* __restrict__ slots,
                                                        int* __restrict__ tok2row) {
    int i = blockIdx.x * 256 + threadIdx.x;
    int e = i >> 12, pos = i & (CAP - 1);
    if (pos < counts[e])
        tok2row[toks[i] * 2 + slots[i]] = offsets[e] + pos;
}

// ------- gather x rows into compacted k-packed A: xg[s][row][8] -------
__global__ __launch_bounds__(256) void gather_x_kernel(
    const float* __restrict__ x,
    const int* __restrict__ counts, const int* __restrict__ offsets,
    const int* __restrict__ toks,
    unsigned short* __restrict__ xg) {
    int rt = blockIdx.x;
    int e = -1, base = 0, rowbase = 0, cnt = 0;
    for (int ee = 0; ee < N_EXP; ++ee) {
        int c = counts[ee];
        int nt = (c + 63) >> 6;
        if (rt < base + nt) { e = ee; rowbase = (rt - base) << 6; cnt = c; break; }
        base += nt;
    }
    if (e < 0) return;
    int off = offsets[e];
    int kb = blockIdx.y;
    __shared__ unsigned short lds[64][72];
    int t = threadIdx.x;
    int r = t >> 2, ck = t & 3;
    int pos = rowbase + r;
    unsigned short tmp[16];
    if (pos < cnt) {
        int tok = toks[e * CAP + pos];
        const float* src = x + (size_t)tok * D_EMBED + kb * 64 + ck * 16;
#pragma unroll
        for (int i = 0; i < 4; ++i) {
            f32x4 v = *reinterpret_cast<const f32x4*>(src + i * 4);
#pragma unroll
            for (int j = 0; j < 4; ++j) tmp[i * 4 + j] = f2bf(v[j]);
        }
    } else {
#pragma unroll
        for (int i = 0; i < 16; ++i) tmp[i] = 0;
    }
#pragma unroll
    for (int i = 0; i < 16; ++i) lds[r][ck * 16 + i] = tmp[i];
    __syncthreads();
    int sl = t >> 5, rr = (t & 31) * 2;
#pragma unroll
    for (int w = 0; w < 2; ++w) {
        int rw = rr + w;
        if (rowbase + rw >= cnt) continue;
        bf16x8 o;
#pragma unroll
        for (int j = 0; j < 8; ++j) o[j] = (short)lds[rw][sl * 8 + j];
        *reinterpret_cast<bf16x8*>(xg + ((size_t)(kb * 8 + sl) * NROWA + off + rowbase + rw) * 8) = o;
    }
}

// ======= GEMM1: 256x256p, half-K(32) ring-4 pipeline, fine phases, counted vmcnt =======
// grid (x = packed coltile 32, y = rowtile 39): XCD = x%8 -> B panel pinned per XCD
__global__ __launch_bounds__(512, 1) void gemm1_kernel(
    const unsigned short* __restrict__ xg,
    const unsigned short* __restrict__ wt13,
    const int* __restrict__ counts, const int* __restrict__ offsets,
    const float* __restrict__ wgts,
    unsigned short* __restrict__ hp) {
    int rt = blockIdx.y;
    int e = -1, base = 0, rowbase = 0, cnt = 0;
#pragma unroll 1
    for (int ee = 0; ee < N_EXP; ++ee) {
        int c = counts[ee];
        int nt = (c + 255) >> 8;
        if (rt < base + nt) { e = ee; rowbase = (rt - base) << 8; cnt = c; break; }
        base += nt;
    }
    if (e < 0) return;
    int off = offsets[e];
    int colp = blockIdx.x * 256;            // packed col base

    __shared__ __align__(16) char lds[4][32768];    // ring-4 half-K bufs: A 16K | B 16K

    int t = threadIdx.x, lane = t & 63, w = t >> 6;  // 8 waves
    int wr = w >> 2, wc = w & 3;                     // wr 0..1 (128 rows), wc 0..3 (64 pcols)
    int q = lane >> 4, p = lane & 15;
    int w2 = w * 2;

    const unsigned short* wB = wt13 + (size_t)e * D_EMBED * 2 * D_HID;
    const unsigned short* pA = xg + (size_t)(off + rowbase) * 8;

    f32x4 acc[8][4] = {};

    // stage chunk c (0..15) of half-tile h into its ring buffer: 1 A-load + 1 B-load
    auto SC = [&](int h, int c) {
        char* Ls = &lds[h & 3][0];
        size_t gs = (size_t)(h * 4 + (c >> 2));
        gload_lds16(pA + (gs * NROWA + (c & 3) * 64 + lane) * 8, Ls + c * 1024);
        gload_lds16(wB + (gs * (2 * D_HID) + colp + (c & 3) * 64 + lane) * 8,
                    Ls + 16384 + c * 1024);
    };

    SC(0, w2); SC(0, w2 + 1);               // prologue: half-tiles 0,1 (8 loads/thread)
    SC(1, w2); SC(1, w2 + 1);
#pragma unroll 1
    for (int h = 0; h < 32; ++h) {          // K=1024 / 32
        if (h < 30) asm volatile("s_waitcnt vmcnt(4)" ::: "memory");
        else        asm volatile("s_waitcnt vmcnt(0)" ::: "memory");
        __builtin_amdgcn_s_barrier();
        asm volatile("" ::: "memory");
        const char* L = &lds[h & 3][0];
        // ---- phase 0: stage 2 -> read 8 -> 16 MFMA ----
        if (h < 30) SC(h + 2, w2);
        bf16x8 af0[4], bfr[4];
#pragma unroll
        for (int m = 0; m < 4; ++m)
            af0[m] = *reinterpret_cast<const bf16x8*>(L + q * 4096 + (wr * 128 + m * 16 + p) * 16);
#pragma unroll
        for (int n = 0; n < 4; ++n)
            bfr[n] = *reinterpret_cast<const bf16x8*>(L + 16384 + q * 4096 + (wc * 64 + n * 16 + p) * 16);
        __builtin_amdgcn_s_setprio(1);
#pragma unroll
        for (int n = 0; n < 4; ++n)
#pragma unroll
            for (int m = 0; m < 4; ++m)
                acc[m][n] = __builtin_amdgcn_mfma_f32_16x16x32_bf16(af0[m], bfr[n], acc[m][n], 0, 0, 0);
        __builtin_amdgcn_s_setprio(0);
        // ---- phase 1: stage 2 -> read 4 -> 16 MFMA ----
        if (h < 30) SC(h + 2, w2 + 1);
        bf16x8 af1[4];
#pragma unroll
        for (int m = 0; m < 4; ++m)
            af1[m] = *reinterpret_cast<const bf16x8*>(L + q * 4096 + (wr * 128 + (m + 4) * 16 + p) * 16);
        __builtin_amdgcn_s_setprio(1);
#pragma unroll
        for (int n = 0; n < 4; ++n)
#pragma unroll
            for (int m = 0; m < 4; ++m)
                acc[m + 4][n] = __builtin_amdgcn_mfma_f32_16x16x32_bf16(af1[m], bfr[n], acc[m + 4][n], 0, 0, 0);
        __builtin_amdgcn_s_setprio(0);
        asm volatile("" ::: "memory");
    }

    // epilogue: pcol-frag pairs (even n = W1, odd n = W3) -> SwiGLU -> hp (k-packed)
#pragma unroll
    for (int m = 0; m < 8; ++m) {
#pragma unroll
        for (int reg = 0; reg < 4; ++reg) {
            int rl = wr * 128 + m * 16 + q * 4 + reg;
            int grow = rowbase + rl;
            if (grow >= cnt) continue;
            float wgt = wgts[e * CAP + grow];
            size_t row = (size_t)(off + grow);
#pragma unroll
            for (int np = 0; np < 2; ++np) {
                float a1 = acc[m][2 * np][reg];
                float a3 = acc[m][2 * np + 1][reg];
                float hv = (a1 / (1.0f + __expf(-a1))) * a3 * wgt;
                int rc = (blockIdx.x * 8 + wc * 2 + np) * 16 + p;   // real col
                hp[((size_t)(rc >> 3) * NROWA + row) * 8 + (rc & 7)] = f2bf(hv);
            }
        }
    }
}

// ======= GEMM2: 256x256, split-K=4, same half-K ring-4 fine-phase pipeline =======
// grid (x = coltile 4, y = rowtile 39, z = split 4)
__global__ __launch_bounds__(512, 1) void gemm2_kernel(
    const unsigned short* __restrict__ hp,
    const unsigned short* __restrict__ wt2,
    const int* __restrict__ counts, const int* __restrict__ offsets,
    float* __restrict__ pbuf) {
    int rt = blockIdx.y;
    int e = -1, base = 0, rowbase = 0, cnt = 0;
#pragma unroll 1
    for (int ee = 0; ee < N_EXP; ++ee) {
        int c = counts[ee];
        int nt = (c + 255) >> 8;
        if (rt < base + nt) { e = ee; rowbase = (rt - base) << 8; cnt = c; break; }
        base += nt;
    }
    if (e < 0) return;
    int off = offsets[e];
    int colb = blockIdx.x * 256;
    int s2 = blockIdx.z;

    __shared__ __align__(16) char lds[4][32768];

    int t = threadIdx.x, lane = t & 63, w = t >> 6;
    int wr = w >> 2, wc = w & 3;
    int q = lane >> 4, p = lane & 15;
    int w2 = w * 2;

    const unsigned short* wB = wt2 + (size_t)e * D_HID * D_EMBED;
    const unsigned short* pA = hp + (size_t)(off + rowbase) * 8;

    f32x4 acc[8][4] = {};

    auto SC = [&](int h, int c) {
        char* Ls = &lds[h & 3][0];
        size_t gs = (size_t)(s2 * 128 + h * 4 + (c >> 2));
        gload_lds16(pA + (gs * NROWA + (c & 3) * 64 + lane) * 8, Ls + c * 1024);
        gload_lds16(wB + (gs * D_EMBED + colb + (c & 3) * 64 + lane) * 8,
                    Ls + 16384 + c * 1024);
    };

    SC(0, w2); SC(0, w2 + 1);
    SC(1, w2); SC(1, w2 + 1);
#pragma unroll 1
    for (int h = 0; h < 32; ++h) {          // 1024 k per split / 32
        if (h < 30) asm volatile("s_waitcnt vmcnt(4)" ::: "memory");
        else        asm volatile("s_waitcnt vmcnt(0)" ::: "memory");
        __builtin_amdgcn_s_barrier();
        asm volatile("" ::: "memory");
        const char* L = &lds[h & 3][0];
        if (h < 30) SC(h + 2, w2);
        bf16x8 af0[4], bfr[4];
#pragma unroll
        for (int m = 0; m < 4; ++m)
            af0[m] = *reinterpret_cast<const bf16x8*>(L + q * 4096 + (wr * 128 + m * 16 + p) * 16);
#pragma unroll
        for (int n = 0; n < 4; ++n)
            bfr[n] = *reinterpret_cast<const bf16x8*>(L + 16384 + q * 4096 + (wc * 64 + n * 16 + p) * 16);
        __builtin_amdgcn_s_setprio(1);
#pragma unroll
        for (int n = 0; n < 4; ++n)
#pragma unroll
            for (int m = 0; m < 4; ++m)
                acc[m][n] = __builtin_amdgcn_mfma_f32_16x16x32_bf16(af0[m], bfr[n], acc[m][n], 0, 0, 0);
        __builtin_amdgcn_s_setprio(0);
        if (h < 30) SC(h + 2, w2 + 1);
        bf16x8 af1[4];
#pragma unroll
        for (int m = 0; m < 4; ++m)
            af1[m] = *reinterpret_cast<const bf16x8*>(L + q * 4096 + (wr * 128 + (m + 4) * 16 + p) * 16);
        __builtin_amdgcn_s_setprio(1);
#pragma unroll
        for (int n = 0; n < 4; ++n)
#pragma unroll
            for (int m = 0; m < 4; ++m)
                acc[m + 4][n] = __builtin_amdgcn_mfma_f32_16x16x32_bf16(af1[m], bfr[n], acc[m + 4][n], 0, 0, 0);
        __builtin_amdgcn_s_setprio(0);
        asm volatile("" ::: "memory");
    }

    float* pb = pbuf + (size_t)s2 * 8192 * D_EMBED;
#pragma unroll
    for (int m = 0; m < 8; ++m)
#pragma unroll
        for (int reg = 0; reg < 4; ++reg) {
            int rl = wr * 128 + m * 16 + q * 4 + reg;
            int grow = rowbase + rl;
            if (grow >= cnt) continue;
            float* dst = pb + (size_t)(off + grow) * D_EMBED + colb + wc * 64;
#pragma unroll
            for (int n = 0; n < 4; ++n) dst[n * 16 + p] = acc[m][n][reg];
        }
}

// ---------------- combine: out[tok] = sum over 2 rows x 4 k-splits ----------------
__global__ __launch_bounds__(256) void combine_kernel(const float* __restrict__ pbuf,
                                                      const int* __restrict__ tok2row,
                                                      float* __restrict__ out) {
    int i = blockIdx.x * 256 + threadIdx.x;
    int tok = i >> 8, c = (i & 255) * 4;
    int r0 = tok2row[tok * 2], r1 = tok2row[tok * 2 + 1];
    const size_t SP = (size_t)8192 * D_EMBED;
    f32x4 s = {0.f, 0.f, 0.f, 0.f};
#pragma unroll
    for (int sp = 0; sp < 4; ++sp) {
        f32x4 a = *reinterpret_cast<const f32x4*>(pbuf + sp * SP + (size_t)r0 * D_EMBED + c);
        f32x4 b = *reinterpret_cast<const f32x4*>(pbuf + sp * SP + (size_t)r1 * D_EMBED + c);
        s = s + a + b;
    }
    *reinterpret_cast<f32x4*>(out + (size_t)tok * D_EMBED + c) = s;
}

extern "C" void kernel_launch(void* const* d_in, const int* in_sizes, int n_in,
                              void* d_out, int out_size, void* d_ws, size_t ws_size,
                              hipStream_t stream) {
    const float* x  = (const float*)d_in[0];
    const float* Wg = (const float*)d_in[1];
    const float* W1 = (const float*)d_in[2];
    const float* W3 = (const float*)d_in[3];
    const float* W2 = (const float*)d_in[4];
    float* out = (float*)d_out;

    char* ws = (char*)d_ws;
    size_t szW = (size_t)N_EXP * D_EMBED * D_HID;
    unsigned short* wt13 = (unsigned short*)ws; ws += szW * 2 * 2;     // 128 MB
    unsigned short* wt2  = (unsigned short*)ws; ws += szW * 2;         // 64 MB
    unsigned short* hp   = (unsigned short*)ws; ws += (size_t)(D_HID / 8) * NROWA * 8 * 2;
    unsigned short* xg   = (unsigned short*)ws; ws += (size_t)(D_EMBED / 8) * NROWA * 8 * 2;
    int*   toks    = (int*)ws;   ws += (size_t)N_EXP * CAP * 4;
    float* wgts    = (float*)ws; ws += (size_t)N_EXP * CAP * 4;
    int*   slots   = (int*)ws;   ws += (size_t)N_EXP * CAP * 4;
    int*   tok2row = (int*)ws;   ws += (size_t)N_TOK * 2 * 4;
    int*   counts  = (int*)ws;   ws += 8 * 4;
    int*   offsets = (int*)ws;   ws += 8 * 4;
    // pbuf (128 MB: 4 splits x 8192 x 1024 f32) aliases wt13 (128 MB, dead after gemm1)
    float* pbuf = (float*)wt13;

    hipMemsetAsync(counts, 0, 8 * sizeof(int), stream);

    pack_w13<<<dim3(128, 16, N_EXP), 256, 0, stream>>>(W1, W3, wt13);
    pack_w<<<dim3(D_EMBED / 64, D_HID / 64, N_EXP), 256, 0, stream>>>(W2, wt2, D_HID, D_EMBED);
    gate_kernel<<<N_TOK / 4, 256, 0, stream>>>(x, Wg, counts, toks, wgts, slots);
    prefix_kernel<<<1, 64, 0, stream>>>(counts, offsets);
    build_map_kernel<<<(N_EXP * CAP) / 256, 256, 0, stream>>>(counts, offsets, toks, slots, tok2row);
    gather_x_kernel<<<dim3(136, D_EMBED / 64), 256, 0, stream>>>(x, counts, offsets, toks, xg);
    gemm1_kernel<<<dim3(32, 39), 512, 0, stream>>>(xg, wt13, counts, offsets, wgts, hp);
    gemm2_kernel<<<dim3(4, 39, 4), 512, 0, stream>>>(hp, wt2, counts, offsets, pbuf);
    combine_kernel<<<(N_TOK * 256) / 256, 256, 0, stream>>>(pbuf, tok2row, out);
}

// Round 9
// 542.380 us; speedup vs baseline: 1.0224x; 1.0146x over previous
//
#include <hip/hip_runtime.h>
#include <hip/hip_bf16.h>
#include <stdint.h>

#define D_EMBED 1024
#define D_HID   4096
#define N_TOK   4096
#define N_EXP   8
#define CAP     4096
#define NROWA   8448            // 8192 rows + slack for 256-row tile overshoot

typedef __attribute__((ext_vector_type(4))) float f32x4;
typedef __attribute__((ext_vector_type(8))) short bf16x8;

__device__ __forceinline__ unsigned short f2bf(float f) {
    unsigned int u = __builtin_bit_cast(unsigned int, f);
    u += 0x7fffu + ((u >> 16) & 1u);          // round-to-nearest-even
    return (unsigned short)(u >> 16);
}

__device__ __forceinline__ void gload_lds16(const void* g, void* l) {
    __builtin_amdgcn_global_load_lds(
        (const __attribute__((address_space(1))) unsigned int*)g,
        (__attribute__((address_space(3))) unsigned int*)l,
        16, 0, 0);
}

// ------- pack W [E][R][C] f32 -> tiled bf16 [E][R/8 ks][C][8 j] (for W2) -------
__global__ __launch_bounds__(256) void pack_w(const float* __restrict__ W,
                                              unsigned short* __restrict__ out, int R, int C) {
    int e = blockIdx.z, kb = blockIdx.y, cb = blockIdx.x;
    const float* Wp = W + (size_t)e * R * C + (size_t)(kb * 64) * C + cb * 64;
    unsigned short* op = out + (size_t)e * R * C;
    __shared__ unsigned short lds[64][72];
    int t = threadIdx.x;
    int r = t >> 2;
    int c0 = (t & 3) << 4;
    const float* src = Wp + (size_t)r * C + c0;
#pragma unroll
    for (int i = 0; i < 2; ++i) {
        f32x4 a = *reinterpret_cast<const f32x4*>(src + i * 8);
        f32x4 b = *reinterpret_cast<const f32x4*>(src + i * 8 + 4);
        bf16x8 o;
        o[0]=(short)f2bf(a[0]); o[1]=(short)f2bf(a[1]); o[2]=(short)f2bf(a[2]); o[3]=(short)f2bf(a[3]);
        o[4]=(short)f2bf(b[0]); o[5]=(short)f2bf(b[1]); o[6]=(short)f2bf(b[2]); o[7]=(short)f2bf(b[3]);
        *reinterpret_cast<bf16x8*>(&lds[r][c0 + i * 8]) = o;
    }
    __syncthreads();
#pragma unroll
    for (int i = 0; i < 2; ++i) {
        int cell = i * 256 + t;
        int ksl = cell >> 6, col = cell & 63;
        bf16x8 o;
#pragma unroll
        for (int j = 0; j < 8; ++j) o[j] = (short)lds[ksl * 8 + j][col];
        *reinterpret_cast<bf16x8*>(op + ((size_t)(kb * 8 + ksl) * C + cb * 64 + col) * 8) = o;
    }
}

// ------- pack W1,W3 interleaved at 16-col granularity -------
__global__ __launch_bounds__(256) void pack_w13(const float* __restrict__ W1,
                                                const float* __restrict__ W3,
                                                unsigned short* __restrict__ out) {
    int e = blockIdx.z, kb = blockIdx.y, cb = blockIdx.x;   // cb: 64 packed cols = 32 real each
    size_t ebase = (size_t)e * D_EMBED * D_HID;
    const float* b1 = W1 + ebase + (size_t)(kb * 64) * D_HID + cb * 32;
    const float* b3 = W3 + ebase + (size_t)(kb * 64) * D_HID + cb * 32;
    unsigned short* op = out + (size_t)e * D_EMBED * 2 * D_HID;
    __shared__ unsigned short lds[64][72];   // cols: [W1a 16][W1b 16][W3a 16][W3b 16]
    int t = threadIdx.x;
    int r = t >> 2, ck = t & 3;
    const float* src = (ck >= 2 ? b3 : b1) + (size_t)r * D_HID + (ck & 1) * 16;
#pragma unroll
    for (int i = 0; i < 2; ++i) {
        f32x4 a = *reinterpret_cast<const f32x4*>(src + i * 8);
        f32x4 b = *reinterpret_cast<const f32x4*>(src + i * 8 + 4);
        bf16x8 o;
        o[0]=(short)f2bf(a[0]); o[1]=(short)f2bf(a[1]); o[2]=(short)f2bf(a[2]); o[3]=(short)f2bf(a[3]);
        o[4]=(short)f2bf(b[0]); o[5]=(short)f2bf(b[1]); o[6]=(short)f2bf(b[2]); o[7]=(short)f2bf(b[3]);
        *reinterpret_cast<bf16x8*>(&lds[r][ck * 16 + i * 8]) = o;
    }
    __syncthreads();
#pragma unroll
    for (int i = 0; i < 2; ++i) {
        int cell = i * 256 + t;
        int ksl = cell >> 6, pcp = cell & 63;
        int lcol = ((pcp >> 4) & 1) * 32 + ((pcp >> 5) & 1) * 16 + (pcp & 15);
        bf16x8 o;
#pragma unroll
        for (int j = 0; j < 8; ++j) o[j] = (short)lds[ksl * 8 + j][lcol];
        *reinterpret_cast<bf16x8*>(op + ((size_t)(kb * 8 + ksl) * (2 * D_HID) + cb * 64 + pcp) * 8) = o;
    }
}

// ---------------- gating ----------------
__global__ __launch_bounds__(256) void gate_kernel(const float* __restrict__ x,
                                                   const float* __restrict__ Wg,
                                                   int* __restrict__ counts,
                                                   int* __restrict__ toks,
                                                   float* __restrict__ wgts,
                                                   int* __restrict__ slots) {
    int wave = threadIdx.x >> 6;
    int lane = threadIdx.x & 63;
    int tok = blockIdx.x * 4 + wave;
    const float* xp = x + (size_t)tok * D_EMBED;
    float acc[8] = {0, 0, 0, 0, 0, 0, 0, 0};
#pragma unroll
    for (int i = 0; i < 16; ++i) {
        int d = lane + 64 * i;
        float xv = xp[d];
        f32x4 w0 = *reinterpret_cast<const f32x4*>(Wg + (size_t)d * 8);
        f32x4 w1 = *reinterpret_cast<const f32x4*>(Wg + (size_t)d * 8 + 4);
        acc[0] += xv * w0[0]; acc[1] += xv * w0[1]; acc[2] += xv * w0[2]; acc[3] += xv * w0[3];
        acc[4] += xv * w1[0]; acc[5] += xv * w1[1]; acc[6] += xv * w1[2]; acc[7] += xv * w1[3];
    }
#pragma unroll
    for (int e = 0; e < 8; ++e)
        for (int s = 32; s; s >>= 1) acc[e] += __shfl_xor(acc[e], s, 64);
    if (lane == 0) {
        int i0 = 0; float v0 = acc[0];
#pragma unroll
        for (int e = 1; e < 8; ++e) if (acc[e] > v0) { v0 = acc[e]; i0 = e; }
        int i1 = -1; float v1 = -1e30f;
#pragma unroll
        for (int e = 0; e < 8; ++e) if (e != i0 && acc[e] > v1) { v1 = acc[e]; i1 = e; }
        float ex = __expf(v1 - v0);
        float w0 = 1.0f / (1.0f + ex);
        float w1 = 1.0f - w0;
        int p0 = atomicAdd(&counts[i0], 1);
        toks[i0 * CAP + p0] = tok; wgts[i0 * CAP + p0] = w0; slots[i0 * CAP + p0] = 0;
        int p1 = atomicAdd(&counts[i1], 1);
        toks[i1 * CAP + p1] = tok; wgts[i1 * CAP + p1] = w1; slots[i1 * CAP + p1] = 1;
    }
}

__global__ void prefix_kernel(const int* __restrict__ counts, int* __restrict__ offsets) {
    if (threadIdx.x == 0) {
        int s = 0;
        for (int e = 0; e < N_EXP; ++e) { offsets[e] = s; s += counts[e]; }
    }
}

__global__ __launch_bounds__(256) void build_map_kernel(const int* __restrict__ counts,
                                                        const int* __restrict__ offsets,
                                                        const int* __restrict__ toks,
                                                        const int* __restrict__ slots,
                                                        int* __restrict__ tok2row) {
    int i = blockIdx.x * 256 + threadIdx.x;
    int e = i >> 12, pos = i & (CAP - 1);
    if (pos < counts[e])
        tok2row[toks[i] * 2 + slots[i]] = offsets[e] + pos;
}

// ------- gather x rows into compacted k-packed A: xg[s][row][8] -------
__global__ __launch_bounds__(256) void gather_x_kernel(
    const float* __restrict__ x,
    const int* __restrict__ counts, const int* __restrict__ offsets,
    const int* __restrict__ toks,
    unsigned short* __restrict__ xg) {
    int rt = blockIdx.x;
    int e = -1, base = 0, rowbase = 0, cnt = 0;
    for (int ee = 0; ee < N_EXP; ++ee) {
        int c = counts[ee];
        int nt = (c + 63) >> 6;
        if (rt < base + nt) { e = ee; rowbase = (rt - base) << 6; cnt = c; break; }
        base += nt;
    }
    if (e < 0) return;
    int off = offsets[e];
    int kb = blockIdx.y;
    __shared__ unsigned short lds[64][72];
    int t = threadIdx.x;
    int r = t >> 2, ck = t & 3;
    int pos = rowbase + r;
    unsigned short tmp[16];
    if (pos < cnt) {
        int tok = toks[e * CAP + pos];
        const float* src = x + (size_t)tok * D_EMBED + kb * 64 + ck * 16;
#pragma unroll
        for (int i = 0; i < 4; ++i) {
            f32x4 v = *reinterpret_cast<const f32x4*>(src + i * 4);
#pragma unroll
            for (int j = 0; j < 4; ++j) tmp[i * 4 + j] = f2bf(v[j]);
        }
    } else {
#pragma unroll
        for (int i = 0; i < 16; ++i) tmp[i] = 0;
    }
#pragma unroll
    for (int i = 0; i < 16; ++i) lds[r][ck * 16 + i] = tmp[i];
    __syncthreads();
    int sl = t >> 5, rr = (t & 31) * 2;
#pragma unroll
    for (int w = 0; w < 2; ++w) {
        int rw = rr + w;
        if (rowbase + rw >= cnt) continue;
        bf16x8 o;
#pragma unroll
        for (int j = 0; j < 8; ++j) o[j] = (short)lds[rw][sl * 8 + j];
        *reinterpret_cast<bf16x8*>(xg + ((size_t)(kb * 8 + sl) * NROWA + off + rowbase + rw) * 8) = o;
    }
}

// ======= GEMM1: 256x256p, half-K(32) ring-4, m201-style dual-barrier phases =======
// grid (x = packed coltile 32, y = rowtile 39): XCD = x%8 -> B panel pinned per XCD
__global__ __launch_bounds__(512, 1) void gemm1_kernel(
    const unsigned short* __restrict__ xg,
    const unsigned short* __restrict__ wt13,
    const int* __restrict__ counts, const int* __restrict__ offsets,
    const float* __restrict__ wgts,
    unsigned short* __restrict__ hp) {
    int rt = blockIdx.y;
    int e = -1, base = 0, rowbase = 0, cnt = 0;
#pragma unroll 1
    for (int ee = 0; ee < N_EXP; ++ee) {
        int c = counts[ee];
        int nt = (c + 255) >> 8;
        if (rt < base + nt) { e = ee; rowbase = (rt - base) << 8; cnt = c; break; }
        base += nt;
    }
    if (e < 0) return;
    int off = offsets[e];
    int colp = blockIdx.x * 256;            // packed col base

    __shared__ __align__(16) char lds[4][32768];    // ring-4 slots: A 16K | B 16K

    int t = threadIdx.x, lane = t & 63, w = t >> 6;  // 8 waves
    int wr = w >> 2, wc = w & 3;                     // wr: rows wr*128..; wc: pcols wc*64..
    int q = lane >> 4, p = lane & 15;

    const unsigned short* wB = wt13 + (size_t)e * D_EMBED * 2 * D_HID;
    const unsigned short* pA = xg + (size_t)(off + rowbase) * 8;

    f32x4 acc[8][4] = {};

    // stage part j (0/1) of half-tile h into slot h&3 (2 gloads/thread/part)
    auto STG = [&](int h, int j) {
        char* L = &lds[h & 3][0];
        int flat = j * 512 + t;                 // 0..1023: sl = flat>>8, row/pcol = flat&255
        size_t gs = (size_t)(h * 4 + (flat >> 8));
        int rc = flat & 255;
        gload_lds16(pA + (gs * NROWA + rc) * 8, L + flat * 16);
        gload_lds16(wB + (gs * (2 * D_HID) + colp + rc) * 8, L + 16384 + flat * 16);
    };

    // prologue: slots 0,1 fully staged; publish slot 0
    STG(0, 0); STG(0, 1); STG(1, 0); STG(1, 1);
    asm volatile("s_waitcnt vmcnt(4)" ::: "memory");    // slot0's 4 landed (slot1's fly)
    __builtin_amdgcn_s_barrier();
    asm volatile("" ::: "memory");

#pragma unroll 1
    for (int h = 0; h < 32; ++h) {          // K=1024, half-K=32
        const char* L = &lds[h & 3][0];
        // ---- region A: stage p0(h+2) | 12 ds_reads(slot h) | barrier | 16 MFMA n=0,1 ----
        if (h < 30) STG(h + 2, 0);
        bf16x8 af[8], bf[4];
#pragma unroll
        for (int m = 0; m < 8; ++m)
            af[m] = *reinterpret_cast<const bf16x8*>(L + (q * 256 + wr * 128 + m * 16 + p) * 16);
#pragma unroll
        for (int n = 0; n < 4; ++n)
            bf[n] = *reinterpret_cast<const bf16x8*>(L + 16384 + (q * 256 + wc * 64 + n * 16 + p) * 16);
        asm volatile("" ::: "memory");
        __builtin_amdgcn_s_barrier();
        __builtin_amdgcn_s_setprio(1);
#pragma unroll
        for (int n = 0; n < 2; ++n)
#pragma unroll
            for (int m = 0; m < 8; ++m)
                acc[m][n] = __builtin_amdgcn_mfma_f32_16x16x32_bf16(af[m], bf[n], acc[m][n], 0, 0, 0);
        __builtin_amdgcn_s_setprio(0);
        asm volatile("" ::: "memory");
        // ---- region B: counted vmcnt (slot h+1 landed) | stage p1(h+2) | barrier | 16 MFMA n=2,3 ----
        if (h < 30) asm volatile("s_waitcnt vmcnt(2)" ::: "memory");
        else        asm volatile("s_waitcnt vmcnt(0)" ::: "memory");
        if (h < 30) STG(h + 2, 1);
        asm volatile("" ::: "memory");
        __builtin_amdgcn_s_barrier();       // publish slot h+1
        __builtin_amdgcn_s_setprio(1);
#pragma unroll
        for (int n = 2; n < 4; ++n)
#pragma unroll
            for (int m = 0; m < 8; ++m)
                acc[m][n] = __builtin_amdgcn_mfma_f32_16x16x32_bf16(af[m], bf[n], acc[m][n], 0, 0, 0);
        __builtin_amdgcn_s_setprio(0);
        asm volatile("" ::: "memory");
    }

    // epilogue: pcol-frag pairs (even n = W1, odd n = W3) -> SwiGLU -> hp (k-packed)
#pragma unroll
    for (int m = 0; m < 8; ++m) {
#pragma unroll
        for (int reg = 0; reg < 4; ++reg) {
            int rl = wr * 128 + m * 16 + q * 4 + reg;
            int grow = rowbase + rl;
            if (grow >= cnt) continue;
            float wgt = wgts[e * CAP + grow];
            size_t row = (size_t)(off + grow);
#pragma unroll
            for (int np = 0; np < 2; ++np) {
                float a1 = acc[m][2 * np][reg];
                float a3 = acc[m][2 * np + 1][reg];
                float hv = (a1 / (1.0f + __expf(-a1))) * a3 * wgt;
                int rc = (blockIdx.x * 8 + wc * 2 + np) * 16 + p;   // real col
                hp[((size_t)(rc >> 3) * NROWA + row) * 8 + (rc & 7)] = f2bf(hv);
            }
        }
    }
}

// ======= GEMM2: 256x256, split-K=4, same m201-style pipeline =======
// grid (x = coltile 4, y = rowtile 39, z = split 4)
__global__ __launch_bounds__(512, 1) void gemm2_kernel(
    const unsigned short* __restrict__ hp,
    const unsigned short* __restrict__ wt2,
    const int* __restrict__ counts, const int* __restrict__ offsets,
    float* __restrict__ pbuf) {
    int rt = blockIdx.y;
    int e = -1, base = 0, rowbase = 0, cnt = 0;
#pragma unroll 1
    for (int ee = 0; ee < N_EXP; ++ee) {
        int c = counts[ee];
        int nt = (c + 255) >> 8;
        if (rt < base + nt) { e = ee; rowbase = (rt - base) << 8; cnt = c; break; }
        base += nt;
    }
    if (e < 0) return;
    int off = offsets[e];
    int colb = blockIdx.x * 256;
    int s2 = blockIdx.z;

    __shared__ __align__(16) char lds[4][32768];

    int t = threadIdx.x, lane = t & 63, w = t >> 6;
    int wr = w >> 2, wc = w & 3;
    int q = lane >> 4, p = lane & 15;

    const unsigned short* wB = wt2 + (size_t)e * D_HID * D_EMBED;
    const unsigned short* pA = hp + (size_t)(off + rowbase) * 8;

    f32x4 acc[8][4] = {};

    auto STG = [&](int h, int j) {
        char* L = &lds[h & 3][0];
        int flat = j * 512 + t;
        size_t gs = (size_t)(s2 * 128 + h * 4 + (flat >> 8));
        int rc = flat & 255;
        gload_lds16(pA + (gs * NROWA + rc) * 8, L + flat * 16);
        gload_lds16(wB + (gs * D_EMBED + colb + rc) * 8, L + 16384 + flat * 16);
    };

    STG(0, 0); STG(0, 1); STG(1, 0); STG(1, 1);
    asm volatile("s_waitcnt vmcnt(4)" ::: "memory");
    __builtin_amdgcn_s_barrier();
    asm volatile("" ::: "memory");

#pragma unroll 1
    for (int h = 0; h < 32; ++h) {          // 1024 k per split, half-K=32
        const char* L = &lds[h & 3][0];
        if (h < 30) STG(h + 2, 0);
        bf16x8 af[8], bf[4];
#pragma unroll
        for (int m = 0; m < 8; ++m)
            af[m] = *reinterpret_cast<const bf16x8*>(L + (q * 256 + wr * 128 + m * 16 + p) * 16);
#pragma unroll
        for (int n = 0; n < 4; ++n)
            bf[n] = *reinterpret_cast<const bf16x8*>(L + 16384 + (q * 256 + wc * 64 + n * 16 + p) * 16);
        asm volatile("" ::: "memory");
        __builtin_amdgcn_s_barrier();
        __builtin_amdgcn_s_setprio(1);
#pragma unroll
        for (int n = 0; n < 2; ++n)
#pragma unroll
            for (int m = 0; m < 8; ++m)
                acc[m][n] = __builtin_amdgcn_mfma_f32_16x16x32_bf16(af[m], bf[n], acc[m][n], 0, 0, 0);
        __builtin_amdgcn_s_setprio(0);
        asm volatile("" ::: "memory");
        if (h < 30) asm volatile("s_waitcnt vmcnt(2)" ::: "memory");
        else        asm volatile("s_waitcnt vmcnt(0)" ::: "memory");
        if (h < 30) STG(h + 2, 1);
        asm volatile("" ::: "memory");
        __builtin_amdgcn_s_barrier();
        __builtin_amdgcn_s_setprio(1);
#pragma unroll
        for (int n = 2; n < 4; ++n)
#pragma unroll
            for (int m = 0; m < 8; ++m)
                acc[m][n] = __builtin_amdgcn_mfma_f32_16x16x32_bf16(af[m], bf[n], acc[m][n], 0, 0, 0);
        __builtin_amdgcn_s_setprio(0);
        asm volatile("" ::: "memory");
    }

    float* pb = pbuf + (size_t)s2 * 8192 * D_EMBED;
#pragma unroll
    for (int m = 0; m < 8; ++m)
#pragma unroll
        for (int reg = 0; reg < 4; ++reg) {
            int rl = wr * 128 + m * 16 + q * 4 + reg;
            int grow = rowbase + rl;
            if (grow >= cnt) continue;
            float* dst = pb + (size_t)(off + grow) * D_EMBED + colb + wc * 64;
#pragma unroll
            for (int n = 0; n < 4; ++n) dst[n * 16 + p] = acc[m][n][reg];
        }
}

// ---------------- combine: out[tok] = sum over 2 rows x 4 k-splits ----------------
__global__ __launch_bounds__(256) void combine_kernel(const float* __restrict__ pbuf,
                                                      const int* __restrict__ tok2row,
                                                      float* __restrict__ out) {
    int i = blockIdx.x * 256 + threadIdx.x;
    int tok = i >> 8, c = (i & 255) * 4;
    int r0 = tok2row[tok * 2], r1 = tok2row[tok * 2 + 1];
    const size_t SP = (size_t)8192 * D_EMBED;
    f32x4 s = {0.f, 0.f, 0.f, 0.f};
#pragma unroll
    for (int sp = 0; sp < 4; ++sp) {
        f32x4 a = *reinterpret_cast<const f32x4*>(pbuf + sp * SP + (size_t)r0 * D_EMBED + c);
        f32x4 b = *reinterpret_cast<const f32x4*>(pbuf + sp * SP + (size_t)r1 * D_EMBED + c);
        s = s + a + b;
    }
    *reinterpret_cast<f32x4*>(out + (size_t)tok * D_EMBED + c) = s;
}

extern "C" void kernel_launch(void* const* d_in, const int* in_sizes, int n_in,
                              void* d_out, int out_size, void* d_ws, size_t ws_size,
                              hipStream_t stream) {
    const float* x  = (const float*)d_in[0];
    const float* Wg = (const float*)d_in[1];
    const float* W1 = (const float*)d_in[2];
    const float* W3 = (const float*)d_in[3];
    const float* W2 = (const float*)d_in[4];
    float* out = (float*)d_out;

    char* ws = (char*)d_ws;
    size_t szW = (size_t)N_EXP * D_EMBED * D_HID;
    unsigned short* wt13 = (unsigned short*)ws; ws += szW * 2 * 2;     // 128 MB
    unsigned short* wt2  = (unsigned short*)ws; ws += szW * 2;         // 64 MB
    unsigned short* hp   = (unsigned short*)ws; ws += (size_t)(D_HID / 8) * NROWA * 8 * 2;
    unsigned short* xg   = (unsigned short*)ws; ws += (size_t)(D_EMBED / 8) * NROWA * 8 * 2;
    int*   toks    = (int*)ws;   ws += (size_t)N_EXP * CAP * 4;
    float* wgts    = (float*)ws; ws += (size_t)N_EXP * CAP * 4;
    int*   slots   = (int*)ws;   ws += (size_t)N_EXP * CAP * 4;
    int*   tok2row = (int*)ws;   ws += (size_t)N_TOK * 2 * 4;
    int*   counts  = (int*)ws;   ws += 8 * 4;
    int*   offsets = (int*)ws;   ws += 8 * 4;
    // pbuf (128 MB: 4 splits x 8192 x 1024 f32) aliases wt13 (128 MB, dead after gemm1)
    float* pbuf = (float*)wt13;

    hipMemsetAsync(counts, 0, 8 * sizeof(int), stream);

    pack_w13<<<dim3(128, 16, N_EXP), 256, 0, stream>>>(W1, W3, wt13);
    pack_w<<<dim3(D_EMBED / 64, D_HID / 64, N_EXP), 256, 0, stream>>>(W2, wt2, D_HID, D_EMBED);
    gate_kernel<<<N_TOK / 4, 256, 0, stream>>>(x, Wg, counts, toks, wgts, slots);
    prefix_kernel<<<1, 64, 0, stream>>>(counts, offsets);
    build_map_kernel<<<(N_EXP * CAP) / 256, 256, 0, stream>>>(counts, offsets, toks, slots, tok2row);
    gather_x_kernel<<<dim3(136, D_EMBED / 64), 256, 0, stream>>>(x, counts, offsets, toks, xg);
    gemm1_kernel<<<dim3(32, 39), 512, 0, stream>>>(xg, wt13, counts, offsets, wgts, hp);
    gemm2_kernel<<<dim3(4, 39, 4), 512, 0, stream>>>(hp, wt2, counts, offsets, pbuf);
    combine_kernel<<<(N_TOK * 256) / 256, 256, 0, stream>>>(pbuf, tok2row, out);
}

// Round 10
// 475.096 us; speedup vs baseline: 1.1672x; 1.1416x over previous
//
#include <hip/hip_runtime.h>
#include <hip/hip_bf16.h>
#include <stdint.h>

#define D_EMBED 1024
#define D_HID   4096
#define N_TOK   4096
#define N_EXP   8
#define CAP     4096
#define NROWA   8448

typedef __attribute__((ext_vector_type(4))) float f32x4;
typedef __attribute__((ext_vector_type(8))) short bf16x8;

__device__ __forceinline__ unsigned short f2bf(float f) {
    unsigned int u = __builtin_bit_cast(unsigned int, f);
    u += 0x7fffu + ((u >> 16) & 1u);
    return (unsigned short)(u >> 16);
}
__device__ __forceinline__ float bf2f(unsigned short h) {
    unsigned int u = ((unsigned int)h) << 16;
    return __builtin_bit_cast(float, u);
}
__device__ __forceinline__ void gload_lds16(const void* g, void* l) {
    __builtin_amdgcn_global_load_lds(
        (const __attribute__((address_space(1))) unsigned int*)g,
        (__attribute__((address_space(3))) unsigned int*)l, 16, 0, 0);
}

// ------- pack W1,W3 interleaved, no LDS: out[e][s][pc][8] = Wx[e][s*8+j][rc] -------
__global__ __launch_bounds__(256) void pack_w13(const float* __restrict__ W1,
                                                const float* __restrict__ W3,
                                                unsigned short* __restrict__ out) {
    int idx = blockIdx.x * 256 + threadIdx.x;      // 2^23 total
    int pc = idx & 8191, s = (idx >> 13) & 127, e = idx >> 20;
    int g = pc >> 4;
    int rc = ((g >> 1) << 4) + (pc & 15);
    const float* src = (g & 1 ? W3 : W1) + (size_t)e * (D_EMBED * D_HID)
                     + (size_t)(s * 8) * D_HID + rc;
    bf16x8 o;
#pragma unroll
    for (int j = 0; j < 8; ++j) o[j] = (short)f2bf(src[(size_t)j * D_HID]);
    *reinterpret_cast<bf16x8*>(out + (size_t)e * (D_EMBED * 2 * D_HID)
                               + ((size_t)s * (2 * D_HID) + pc) * 8) = o;
}

// ------- pack W2, no LDS: out[e][s][col][8] = W[e][s*8+j][col] -------
__global__ __launch_bounds__(256) void pack_w(const float* __restrict__ W,
                                              unsigned short* __restrict__ out) {
    int idx = blockIdx.x * 256 + threadIdx.x;      // 2^22 total
    int col = idx & 1023, s = (idx >> 10) & 511, e = idx >> 19;
    const float* src = W + (size_t)e * (D_HID * D_EMBED) + (size_t)(s * 8) * D_EMBED + col;
    bf16x8 o;
#pragma unroll
    for (int j = 0; j < 8; ++j) o[j] = (short)f2bf(src[(size_t)j * D_EMBED]);
    *reinterpret_cast<bf16x8*>(out + (size_t)e * (D_HID * D_EMBED)
                               + ((size_t)s * D_EMBED + col) * 8) = o;
}

// ---------------- gating ----------------
__global__ __launch_bounds__(256) void gate_kernel(const float* __restrict__ x,
                                                   const float* __restrict__ Wg,
                                                   int* __restrict__ counts,
                                                   int* __restrict__ toks,
                                                   float* __restrict__ wgts,
                                                   int* __restrict__ slots) {
    int wave = threadIdx.x >> 6;
    int lane = threadIdx.x & 63;
    int tok = blockIdx.x * 4 + wave;
    const float* xp = x + (size_t)tok * D_EMBED;
    float acc[8] = {0, 0, 0, 0, 0, 0, 0, 0};
#pragma unroll
    for (int i = 0; i < 16; ++i) {
        int d = lane + 64 * i;
        float xv = xp[d];
        f32x4 w0 = *reinterpret_cast<const f32x4*>(Wg + (size_t)d * 8);
        f32x4 w1 = *reinterpret_cast<const f32x4*>(Wg + (size_t)d * 8 + 4);
        acc[0] += xv * w0[0]; acc[1] += xv * w0[1]; acc[2] += xv * w0[2]; acc[3] += xv * w0[3];
        acc[4] += xv * w1[0]; acc[5] += xv * w1[1]; acc[6] += xv * w1[2]; acc[7] += xv * w1[3];
    }
#pragma unroll
    for (int e = 0; e < 8; ++e)
        for (int s = 32; s; s >>= 1) acc[e] += __shfl_xor(acc[e], s, 64);
    if (lane == 0) {
        int i0 = 0; float v0 = acc[0];
#pragma unroll
        for (int e = 1; e < 8; ++e) if (acc[e] > v0) { v0 = acc[e]; i0 = e; }
        int i1 = -1; float v1 = -1e30f;
#pragma unroll
        for (int e = 0; e < 8; ++e) if (e != i0 && acc[e] > v1) { v1 = acc[e]; i1 = e; }
        float ex = __expf(v1 - v0);
        float w0 = 1.0f / (1.0f + ex);
        float w1 = 1.0f - w0;
        int p0 = atomicAdd(&counts[i0], 1);
        toks[i0 * CAP + p0] = tok; wgts[i0 * CAP + p0] = w0; slots[i0 * CAP + p0] = 0;
        int p1 = atomicAdd(&counts[i1], 1);
        toks[i1 * CAP + p1] = tok; wgts[i1 * CAP + p1] = w1; slots[i1 * CAP + p1] = 1;
    }
}

__global__ __launch_bounds__(256) void build_map_kernel(const int* __restrict__ counts,
                                                        const int* __restrict__ toks,
                                                        const int* __restrict__ slots,
                                                        int* __restrict__ tok2row) {
    int i = blockIdx.x * 256 + threadIdx.x;
    int e = i >> 12, pos = i & (CAP - 1);
    if (pos >= counts[e]) return;
    int off = 0;
    for (int k = 0; k < e; ++k) off += counts[k];
    tok2row[toks[i] * 2 + slots[i]] = off + pos;
}

// ------- gather x rows into compacted k-packed A: xg[s][row][8] -------
__global__ __launch_bounds__(256) void gather_x_kernel(
    const float* __restrict__ x, const int* __restrict__ counts,
    const int* __restrict__ toks, unsigned short* __restrict__ xg) {
    int rt = blockIdx.x;
    int e = -1, tb = 0, osum = 0, rowbase = 0, cnt = 0, off = 0;
    for (int ee = 0; ee < N_EXP; ++ee) {
        int c = counts[ee];
        int nt = (c + 63) >> 6;
        if (rt < tb + nt) { e = ee; rowbase = (rt - tb) << 6; cnt = c; off = osum; break; }
        tb += nt; osum += c;
    }
    if (e < 0) return;
    int kb = blockIdx.y;
    __shared__ unsigned short lds[64][72];
    int t = threadIdx.x;
    int r = t >> 2, ck = t & 3;
    int pos = rowbase + r;
    unsigned short tmp[16];
    if (pos < cnt) {
        int tok = toks[e * CAP + pos];
        const float* src = x + (size_t)tok * D_EMBED + kb * 64 + ck * 16;
#pragma unroll
        for (int i = 0; i < 4; ++i) {
            f32x4 v = *reinterpret_cast<const f32x4*>(src + i * 4);
#pragma unroll
            for (int j = 0; j < 4; ++j) tmp[i * 4 + j] = f2bf(v[j]);
        }
    } else {
#pragma unroll
        for (int i = 0; i < 16; ++i) tmp[i] = 0;
    }
#pragma unroll
    for (int i = 0; i < 16; ++i) lds[r][ck * 16 + i] = tmp[i];
    __syncthreads();
    int sl = t >> 5, rr = (t & 31) * 2;
#pragma unroll
    for (int w = 0; w < 2; ++w) {
        int rw = rr + w;
        if (rowbase + rw >= cnt) continue;
        bf16x8 o;
#pragma unroll
        for (int j = 0; j < 8; ++j) o[j] = (short)lds[rw][sl * 8 + j];
        *reinterpret_cast<bf16x8*>(xg + ((size_t)(kb * 8 + sl) * NROWA + off + rowbase + rw) * 8) = o;
    }
}

// ======= GEMM1: 128 rows x 256 pcols, ring-3 half-K, 512 thr, 2 blocks/CU =======
// grid (x = packed coltile 32, y = rowtile 72): XCD = x%8 -> B panel pinned per XCD
__global__ __launch_bounds__(512, 4) void gemm1_kernel(
    const unsigned short* __restrict__ xg,
    const unsigned short* __restrict__ wt13,
    const int* __restrict__ counts,
    const float* __restrict__ wgts,
    unsigned short* __restrict__ hp) {
    int rt = blockIdx.y;
    int e = -1, tb = 0, osum = 0, rowbase = 0, cnt = 0, off = 0;
#pragma unroll 1
    for (int ee = 0; ee < N_EXP; ++ee) {
        int c = counts[ee];
        int nt = (c + 127) >> 7;
        if (rt < tb + nt) { e = ee; rowbase = (rt - tb) << 7; cnt = c; off = osum; break; }
        tb += nt; osum += c;
    }
    if (e < 0) return;
    int colp = blockIdx.x * 256;

    __shared__ __align__(16) char lds[3][24576];   // slot: A 8K [sl4][row128] | B 16K [sl4][pc256]

    int t = threadIdx.x, lane = t & 63, w = t >> 6;   // 8 waves, 2Mx4N
    int wr = w >> 2, wc = w & 3;
    int q = lane >> 4, p = lane & 15;

    // strength-reduced staging pointers (bytes), 3 gloads per STG
    const size_t ASTEP = (size_t)4 * NROWA * 16;
    const size_t BSTEP = (size_t)4 * (2 * D_HID) * 16;
    const char* aS = (const char*)xg + ((size_t)(t >> 7) * NROWA + off + rowbase + (t & 127)) * 16;
    const char* bS0 = (const char*)wt13 + (size_t)e * D_EMBED * 2 * D_HID * 2
                    + ((size_t)(t >> 8) * (2 * D_HID) + colp + (t & 255)) * 16;
    const char* bS1 = bS0 + (size_t)2 * (2 * D_HID) * 16;

    int wslot = 0;
    auto STG = [&]() {
        char* L = &lds[wslot][0];
        wslot = (wslot == 2) ? 0 : wslot + 1;
        gload_lds16(aS, L + t * 16);                 aS += ASTEP;
        gload_lds16(bS0, L + 8192 + t * 16);         bS0 += BSTEP;
        gload_lds16(bS1, L + 16384 + t * 16);        bS1 += BSTEP;
    };

    f32x4 acc[4][4] = {};

    STG(); STG();
    asm volatile("s_waitcnt vmcnt(3)" ::: "memory");
    __builtin_amdgcn_s_barrier();
    asm volatile("" ::: "memory");

    int rslot = 0;
#pragma unroll 1
    for (int h = 0; h < 32; ++h) {                  // K=1024, half-K=32
        const char* L = &lds[rslot][0];
        rslot = (rslot == 2) ? 0 : rslot + 1;
        if (h < 30) STG();
        bf16x8 af[4], bf[4];
#pragma unroll
        for (int m = 0; m < 4; ++m)
            af[m] = *reinterpret_cast<const bf16x8*>(L + (q * 128 + wr * 64 + m * 16 + p) * 16);
#pragma unroll
        for (int n = 0; n < 4; ++n)
            bf[n] = *reinterpret_cast<const bf16x8*>(L + 8192 + (q * 256 + wc * 64 + n * 16 + p) * 16);
        asm volatile("" ::: "memory");
        __builtin_amdgcn_s_barrier();
        __builtin_amdgcn_s_setprio(1);
#pragma unroll
        for (int n = 0; n < 2; ++n)
#pragma unroll
            for (int m = 0; m < 4; ++m)
                acc[m][n] = __builtin_amdgcn_mfma_f32_16x16x32_bf16(af[m], bf[n], acc[m][n], 0, 0, 0);
        __builtin_amdgcn_s_setprio(0);
        asm volatile("" ::: "memory");
        if (h < 30) asm volatile("s_waitcnt vmcnt(3)" ::: "memory");
        else        asm volatile("s_waitcnt vmcnt(0)" ::: "memory");
        __builtin_amdgcn_s_barrier();               // publish slot h+1
        __builtin_amdgcn_s_setprio(1);
#pragma unroll
        for (int n = 2; n < 4; ++n)
#pragma unroll
            for (int m = 0; m < 4; ++m)
                acc[m][n] = __builtin_amdgcn_mfma_f32_16x16x32_bf16(af[m], bf[n], acc[m][n], 0, 0, 0);
        __builtin_amdgcn_s_setprio(0);
        asm volatile("" ::: "memory");
    }

    // epilogue: (even n = W1, odd n = W3) -> SwiGLU * gate-weight -> hp (k-packed)
#pragma unroll
    for (int m = 0; m < 4; ++m) {
#pragma unroll
        for (int reg = 0; reg < 4; ++reg) {
            int rl = wr * 64 + m * 16 + q * 4 + reg;
            int grow = rowbase + rl;
            if (grow >= cnt) continue;
            float wgt = wgts[e * CAP + grow];
            size_t row = (size_t)(off + grow);
#pragma unroll
            for (int np = 0; np < 2; ++np) {
                float a1 = acc[m][2 * np][reg];
                float a3 = acc[m][2 * np + 1][reg];
                float hv = (a1 / (1.0f + __expf(-a1))) * a3 * wgt;
                int rc = (blockIdx.x * 8 + wc * 2 + np) * 16 + p;
                hp[((size_t)(rc >> 3) * NROWA + row) * 8 + (rc & 7)] = f2bf(hv);
            }
        }
    }
}

// ======= GEMM2: 128 rows x 256 cols, split-K=4, same structure, pbuf bf16 =======
// grid (x = coltile 4, y = rowtile 72, z = split 4)
__global__ __launch_bounds__(512, 4) void gemm2_kernel(
    const unsigned short* __restrict__ hp,
    const unsigned short* __restrict__ wt2,
    const int* __restrict__ counts,
    unsigned short* __restrict__ pbuf) {
    int rt = blockIdx.y;
    int e = -1, tb = 0, osum = 0, rowbase = 0, cnt = 0, off = 0;
#pragma unroll 1
    for (int ee = 0; ee < N_EXP; ++ee) {
        int c = counts[ee];
        int nt = (c + 127) >> 7;
        if (rt < tb + nt) { e = ee; rowbase = (rt - tb) << 7; cnt = c; off = osum; break; }
        tb += nt; osum += c;
    }
    if (e < 0) return;
    int colb = blockIdx.x * 256;
    int s2 = blockIdx.z;

    __shared__ __align__(16) char lds[3][24576];

    int t = threadIdx.x, lane = t & 63, w = t >> 6;
    int wr = w >> 2, wc = w & 3;
    int q = lane >> 4, p = lane & 15;

    const size_t ASTEP = (size_t)4 * NROWA * 16;
    const size_t BSTEP = (size_t)4 * D_EMBED * 16;
    const char* aS = (const char*)hp
        + ((size_t)(s2 * 128 + (t >> 7)) * NROWA + off + rowbase + (t & 127)) * 16;
    const char* bS0 = (const char*)wt2 + (size_t)e * D_HID * D_EMBED * 2
        + ((size_t)(s2 * 128 + (t >> 8)) * D_EMBED + colb + (t & 255)) * 16;
    const char* bS1 = bS0 + (size_t)2 * D_EMBED * 16;

    int wslot = 0;
    auto STG = [&]() {
        char* L = &lds[wslot][0];
        wslot = (wslot == 2) ? 0 : wslot + 1;
        gload_lds16(aS, L + t * 16);                 aS += ASTEP;
        gload_lds16(bS0, L + 8192 + t * 16);         bS0 += BSTEP;
        gload_lds16(bS1, L + 16384 + t * 16);        bS1 += BSTEP;
    };

    f32x4 acc[4][4] = {};

    STG(); STG();
    asm volatile("s_waitcnt vmcnt(3)" ::: "memory");
    __builtin_amdgcn_s_barrier();
    asm volatile("" ::: "memory");

    int rslot = 0;
#pragma unroll 1
    for (int h = 0; h < 32; ++h) {                  // 1024 k per split
        const char* L = &lds[rslot][0];
        rslot = (rslot == 2) ? 0 : rslot + 1;
        if (h < 30) STG();
        bf16x8 af[4], bf[4];
#pragma unroll
        for (int m = 0; m < 4; ++m)
            af[m] = *reinterpret_cast<const bf16x8*>(L + (q * 128 + wr * 64 + m * 16 + p) * 16);
#pragma unroll
        for (int n = 0; n < 4; ++n)
            bf[n] = *reinterpret_cast<const bf16x8*>(L + 8192 + (q * 256 + wc * 64 + n * 16 + p) * 16);
        asm volatile("" ::: "memory");
        __builtin_amdgcn_s_barrier();
        __builtin_amdgcn_s_setprio(1);
#pragma unroll
        for (int n = 0; n < 2; ++n)
#pragma unroll
            for (int m = 0; m < 4; ++m)
                acc[m][n] = __builtin_amdgcn_mfma_f32_16x16x32_bf16(af[m], bf[n], acc[m][n], 0, 0, 0);
        __builtin_amdgcn_s_setprio(0);
        asm volatile("" ::: "memory");
        if (h < 30) asm volatile("s_waitcnt vmcnt(3)" ::: "memory");
        else        asm volatile("s_waitcnt vmcnt(0)" ::: "memory");
        __builtin_amdgcn_s_barrier();
        __builtin_amdgcn_s_setprio(1);
#pragma unroll
        for (int n = 2; n < 4; ++n)
#pragma unroll
            for (int m = 0; m < 4; ++m)
                acc[m][n] = __builtin_amdgcn_mfma_f32_16x16x32_bf16(af[m], bf[n], acc[m][n], 0, 0, 0);
        __builtin_amdgcn_s_setprio(0);
        asm volatile("" ::: "memory");
    }

    unsigned short* pb = pbuf + (size_t)s2 * 8192 * D_EMBED;
#pragma unroll
    for (int m = 0; m < 4; ++m)
#pragma unroll
        for (int reg = 0; reg < 4; ++reg) {
            int rl = wr * 64 + m * 16 + q * 4 + reg;
            int grow = rowbase + rl;
            if (grow >= cnt) continue;
            unsigned short* dst = pb + (size_t)(off + grow) * D_EMBED + colb + wc * 64;
#pragma unroll
            for (int n = 0; n < 4; ++n) dst[n * 16 + p] = f2bf(acc[m][n][reg]);
        }
}

// ---------------- combine: out[tok] = sum over 2 rows x 4 k-splits (bf16 pbuf) ----------------
__global__ __launch_bounds__(256) void combine_kernel(const unsigned short* __restrict__ pbuf,
                                                      const int* __restrict__ tok2row,
                                                      float* __restrict__ out) {
    int i = blockIdx.x * 256 + threadIdx.x;        // N_TOK * 128, 8 cols each
    int tok = i >> 7, c0 = (i & 127) * 8;
    int r0 = tok2row[tok * 2], r1 = tok2row[tok * 2 + 1];
    const size_t SP = (size_t)8192 * D_EMBED;
    float s[8] = {0, 0, 0, 0, 0, 0, 0, 0};
#pragma unroll
    for (int sp = 0; sp < 4; ++sp) {
        bf16x8 a = *reinterpret_cast<const bf16x8*>(pbuf + sp * SP + (size_t)r0 * D_EMBED + c0);
        bf16x8 b = *reinterpret_cast<const bf16x8*>(pbuf + sp * SP + (size_t)r1 * D_EMBED + c0);
#pragma unroll
        for (int j = 0; j < 8; ++j)
            s[j] += bf2f((unsigned short)a[j]) + bf2f((unsigned short)b[j]);
    }
    float* op = out + (size_t)tok * D_EMBED + c0;
    f32x4 lo = {s[0], s[1], s[2], s[3]}, hi = {s[4], s[5], s[6], s[7]};
    *reinterpret_cast<f32x4*>(op) = lo;
    *reinterpret_cast<f32x4*>(op + 4) = hi;
}

extern "C" void kernel_launch(void* const* d_in, const int* in_sizes, int n_in,
                              void* d_out, int out_size, void* d_ws, size_t ws_size,
                              hipStream_t stream) {
    const float* x  = (const float*)d_in[0];
    const float* Wg = (const float*)d_in[1];
    const float* W1 = (const float*)d_in[2];
    const float* W3 = (const float*)d_in[3];
    const float* W2 = (const float*)d_in[4];
    float* out = (float*)d_out;

    char* ws = (char*)d_ws;
    size_t szW = (size_t)N_EXP * D_EMBED * D_HID;
    unsigned short* wt13 = (unsigned short*)ws; ws += szW * 2 * 2;     // 128 MB
    unsigned short* wt2  = (unsigned short*)ws; ws += szW * 2;         // 64 MB
    unsigned short* hp   = (unsigned short*)ws; ws += (size_t)(D_HID / 8) * NROWA * 8 * 2;
    unsigned short* xg   = (unsigned short*)ws; ws += (size_t)(D_EMBED / 8) * NROWA * 8 * 2;
    int*   toks    = (int*)ws;   ws += (size_t)N_EXP * CAP * 4;
    float* wgts    = (float*)ws; ws += (size_t)N_EXP * CAP * 4;
    int*   slots   = (int*)ws;   ws += (size_t)N_EXP * CAP * 4;
    int*   tok2row = (int*)ws;   ws += (size_t)N_TOK * 2 * 4;
    int*   counts  = (int*)ws;   ws += 8 * 4;
    // pbuf bf16 (64 MB: 4 splits x 8192 x 1024) aliases wt13 (dead after gemm1)
    unsigned short* pbuf = (unsigned short*)wt13;

    hipMemsetAsync(counts, 0, 8 * sizeof(int), stream);

    pack_w13<<<32768, 256, 0, stream>>>(W1, W3, wt13);
    pack_w<<<16384, 256, 0, stream>>>(W2, wt2);
    gate_kernel<<<N_TOK / 4, 256, 0, stream>>>(x, Wg, counts, toks, wgts, slots);
    build_map_kernel<<<(N_EXP * CAP) / 256, 256, 0, stream>>>(counts, toks, slots, tok2row);
    gather_x_kernel<<<dim3(136, D_EMBED / 64), 256, 0, stream>>>(x, counts, toks, xg);
    gemm1_kernel<<<dim3(32, 72), 512, 0, stream>>>(xg, wt13, counts, wgts, hp);
    gemm2_kernel<<<dim3(4, 72, 4), 512, 0, stream>>>(hp, wt2, counts, pbuf);
    combine_kernel<<<(N_TOK * 128) / 256, 256, 0, stream>>>(pbuf, tok2row, out);
}